// Round 6
// baseline (687.553 us; speedup 1.0000x reference)
//
#include <hip/hip_runtime.h>
#include <math.h>

// ---------------------------------------------------------------------------
// conv1: x[512][1][64][64] -> relu -> maxpool2 -> a1[512][16][32][32]
__global__ void k_conv1(const float* __restrict__ x, const float* __restrict__ w,
                        const float* __restrict__ bias, float* __restrict__ out) {
  int idx = blockIdx.x * 256 + threadIdx.x;
  int ox = idx & 31, oy = (idx >> 5) & 31, oc = (idx >> 10) & 15, n = idx >> 14;
  const float* im = x + n * 4096;
  float wv[9];
#pragma unroll
  for (int i = 0; i < 9; ++i) wv[i] = w[oc * 9 + i];
  float bs = bias[oc];
  float m = 0.f;
#pragma unroll
  for (int dy = 0; dy < 2; ++dy)
#pragma unroll
    for (int dx = 0; dx < 2; ++dx) {
      int cy = oy * 2 + dy, cx = ox * 2 + dx;
      float s = bs;
#pragma unroll
      for (int ky = 0; ky < 3; ++ky) {
        int yy = cy + ky - 1;
        if (yy < 0 || yy >= 64) continue;
#pragma unroll
        for (int kx = 0; kx < 3; ++kx) {
          int xx = cx + kx - 1;
          if (xx < 0 || xx >= 64) continue;
          s += im[yy * 64 + xx] * wv[ky * 3 + kx];
        }
      }
      m = fmaxf(m, fmaxf(s, 0.f));
    }
  out[idx] = m;
}

// ---------------------------------------------------------------------------
// weight prep: w2t[c][tap][32oc], w3t[c][tap][256oc]
__global__ void k_prep_w(const float* __restrict__ w2, float* __restrict__ w2t,
                         const float* __restrict__ w3, float* __restrict__ w3t) {
  int id = blockIdx.x * 256 + threadIdx.x;
  if (id < 73728) {
    int ct = id >> 8, oc = id & 255;
    int c = ct / 9, tap = ct - 9 * c;
    w3t[id] = w3[(oc * 32 + c) * 9 + tap];
  }
  if (id < 4608) {
    int ct = id >> 5, oc = id & 31;
    int c = ct / 9, tap = ct - 9 * c;
    w2t[id] = w2[(oc * 16 + c) * 9 + tap];
  }
}

// ---------------------------------------------------------------------------
// conv2: a1[512][16][32][32] -> relu -> maxpool2 -> a2[n][px=256][oc=32]
__global__ __launch_bounds__(256) void k_conv2(
    const float* __restrict__ a1, const float* __restrict__ w2t,
    const float* __restrict__ bias, float* __restrict__ a2) {
  __shared__ __align__(16) float ins[8 * 1024];
  int n = blockIdx.x, ocg = blockIdx.y;
  int tid = threadIdx.x;
  int py = tid >> 4, px = tid & 15;
  int y0 = 2 * py - 1, x0 = 2 * px - 1;
  float acc[16][4] = {};
  const float* wb = w2t + ocg * 16;
  for (int ph = 0; ph < 2; ++ph) {
    __syncthreads();
    const float4* src = (const float4*)(a1 + n * 16384 + ph * 8192);
    for (int i = tid; i < 2048; i += 256) ((float4*)ins)[i] = src[i];
    __syncthreads();
    for (int c = 0; c < 8; ++c) {
      float wv[4][4];
#pragma unroll
      for (int r = 0; r < 4; ++r) {
        int y = y0 + r;
        bool vy = (y >= 0) && (y < 32);
        int yc = vy ? y : 0;
#pragma unroll
        for (int cc = 0; cc < 4; ++cc) {
          int xx = x0 + cc;
          bool vx = (xx >= 0) && (xx < 32);
          int xc = vx ? xx : 0;
          float t = ins[c * 1024 + yc * 32 + xc];
          wv[r][cc] = (vy && vx) ? t : 0.f;
        }
      }
      int ch = ph * 8 + c;
#pragma unroll
      for (int ky = 0; ky < 3; ++ky)
#pragma unroll
        for (int kx = 0; kx < 3; ++kx) {
          const float* w16 = wb + (ch * 9 + ky * 3 + kx) * 32;
#pragma unroll
          for (int i = 0; i < 4; ++i) {
            float vv = wv[(i >> 1) + ky][(i & 1) + kx];
#pragma unroll
            for (int j = 0; j < 16; ++j) acc[j][i] += vv * w16[j];
          }
        }
    }
  }
  const float* bp = bias + ocg * 16;
  float4 o[4];
#pragma unroll
  for (int j = 0; j < 16; ++j) {
    float m = fmaxf(fmaxf(acc[j][0], acc[j][1]), fmaxf(acc[j][2], acc[j][3]));
    ((float*)o)[j] = fmaxf(m + bp[j], 0.f);
  }
  float4* dst = (float4*)(a2 + (size_t)(n * 256 + tid) * 32 + ocg * 16);
#pragma unroll
  for (int q = 0; q < 4; ++q) dst[q] = o[q];
}

// ---------------------------------------------------------------------------
// conv3 v5: a2[n][px][32ch] -> relu -> mean(HW) -> comb0[t][ch][b]
// grid (512 n, 2 ocb), 512 threads = 8 waves x 16 oc each (128 oc/block).
// 16 oc per lane halves DS reads per FMA vs v4 and quarters staging vs v3;
// bank conflicts now sit far below the 123 us VALU floor. No swizzle
// (round-5 lesson: linear layouts can't break the 72px-stride tr-collapse;
// don't fight it, drown it in arithmetic).
__global__ __launch_bounds__(512, 4) void k_conv3(
    const float* __restrict__ a2, const float* __restrict__ w3t,
    const float* __restrict__ bias, float* __restrict__ comb0) {
  __shared__ __align__(16) float ins[324 * 20];  // 25,920 B
  float4* ins4 = (float4*)ins;
  int n = blockIdx.x, ocb = blockIdx.y;
  int tid = threadIdx.x;
  for (int i = tid; i < 1620; i += 512) ins4[i] = float4{0.f, 0.f, 0.f, 0.f};
  int wvid = __builtin_amdgcn_readfirstlane(tid >> 6);  // 8 waves
  int lane = tid & 63;
  int tr = lane >> 4, tc = lane & 15;
  float acc[4][16] = {};
  const float* wbase = w3t + ocb * 128 + wvid * 16;
  const float4* src = (const float4*)(a2 + (size_t)n * 8192);
  for (int hf = 0; hf < 2; ++hf) {
    __syncthreads();
    for (int i = tid; i < 1024; i += 512) {
      int px = i >> 2, cg = i & 3;
      int p = ((px >> 4) + 1) * 18 + (px & 15) + 1;
      ins4[p * 5 + cg] = src[px * 8 + hf * 4 + cg];
    }
    __syncthreads();
    for (int cg = 0; cg < 4; ++cg) {
      int chb = hf * 16 + cg * 4;
#pragma unroll
      for (int dr = 0; dr < 6; ++dr) {
#pragma unroll
        for (int dc = 0; dc < 3; ++dc) {
          int pp = (4 * tr + dr) * 18 + tc + dc;
          float4 v = ins4[pp * 5 + cg];
#pragma unroll
          for (int c = 0; c < 4; ++c) {
            float vv = ((const float*)&v)[c];
            const int ilo = (dr - 2 < 0) ? 0 : dr - 2;
            const int ihi = (dr < 3) ? dr : 3;
#pragma unroll
            for (int i = ilo; i <= ihi; ++i) {
              const float* w16 = wbase + (((chb + c) * 9 + (dr - i) * 3 + dc) * 256);
#pragma unroll
              for (int j = 0; j < 16; ++j) acc[i][j] += vv * w16[j];
            }
          }
        }
      }
    }
  }
  const float* bp = bias + ocb * 128 + wvid * 16;
  int bb = n >> 4, tt = n & 15;
#pragma unroll
  for (int j = 0; j < 16; ++j) {
    float bj = bp[j];
    float s = 0.f;
#pragma unroll
    for (int i = 0; i < 4; ++i) s += fmaxf(acc[i][j] + bj, 0.f);
#pragma unroll
    for (int off = 32; off; off >>= 1) s += __shfl_down(s, off, 64);
    if (lane == 0) {
      int oc = ocb * 128 + wvid * 16 + j;
      comb0[(size_t)(tt * 768 + oc) * 32 + bb] = s * (1.f / 256.f);
    }
  }
}

// ---------------------------------------------------------------------------
// weight transpose: W[fan][512] -> WT[512][fan], 8 arrays in one launch
struct TPtrs { const float* in[8]; float* out[8]; };

__global__ void k_transpose(TPtrs p) {
  __shared__ float tile[32][33];
  int z = blockIdx.z;
  int fan = (z < 4) ? 768 : 1024;
  int k0 = blockIdx.x * 32, h0 = blockIdx.y * 32;
  if (k0 >= fan) return;
  const float* in = p.in[z];
  float* out = p.out[z];
  int tx = threadIdx.x, ty = threadIdx.y;  // 32 x 8
  for (int r = 0; r < 32; r += 8)
    tile[ty + r][tx] = in[(k0 + ty + r) * 512 + h0 + tx];
  __syncthreads();
  for (int r = 0; r < 32; r += 8)
    out[(h0 + ty + r) * fan + k0 + tx] = tile[tx][ty + r];
}

// ---------------------------------------------------------------------------
// LSTM v4 body: thread = (c = tid>>7, kq = (tid>>3)&15, bq = tid&7).
// c now ABOVE the wave boundary -> each wave reads 64 DISTINCT activation
// float4s per k-step (was 4x duplicated within-wave in v3).
struct LstmArgs {
  const float* comb; float* houtA; float* houtB; float* cT;
  const float* Wf; const float* Wi; const float* Wg; const float* Wo;
  const float* bf; const float* bi; const float* bg; const float* bo;
};

template <int IN>
__device__ __forceinline__ void lstm_body(int h, int tid, const LstmArgs& A,
                                          float* wl, float* gsum, float* pre) {
  constexpr int FAN = IN + 512;
  constexpr int PR = FAN + 4;        // padded gate row (floats), 16B-aligned
  constexpr int KT = FAN / 16;       // k per thread (48 or 64)
  if (tid < FAN / 4) {
    ((float4*)(wl + 0 * PR))[tid] = ((const float4*)(A.Wf + (size_t)h * FAN))[tid];
    ((float4*)(wl + 1 * PR))[tid] = ((const float4*)(A.Wi + (size_t)h * FAN))[tid];
    ((float4*)(wl + 2 * PR))[tid] = ((const float4*)(A.Wg + (size_t)h * FAN))[tid];
    ((float4*)(wl + 3 * PR))[tid] = ((const float4*)(A.Wo + (size_t)h * FAN))[tid];
  }
  __syncthreads();
  const int kq = (tid >> 3) & 15, c = tid >> 7, bq = tid & 7;
  const int kbase = kq * KT;
  const float4* w4 = (const float4*)(wl + c * PR + kbase);
  const float4* a4 = (const float4*)A.comb + bq;  // element k at a4[k*8]
  float acc0 = 0.f, acc1 = 0.f, acc2 = 0.f, acc3 = 0.f;
#pragma unroll
  for (int kk = 0; kk < KT / 4; ++kk) {
    float4 w = w4[kk];
#pragma unroll
    for (int j = 0; j < 4; ++j) {
      float wj = ((const float*)&w)[j];
      float4 a = a4[(size_t)(kbase + kk * 4 + j) * 8];
      acc0 += wj * a.x; acc1 += wj * a.y; acc2 += wj * a.z; acc3 += wj * a.w;
    }
  }
  ((float4*)(gsum + (c * 16 + kq) * 36))[bq] = float4{acc0, acc1, acc2, acc3};
  __syncthreads();
  if (tid < 128) {
    int cc = tid >> 5, b = tid & 31;
    float s = 0.f;
#pragma unroll
    for (int q = 0; q < 16; ++q) s += gsum[(cc * 16 + q) * 36 + b];
    pre[cc * 33 + b] = s;
  }
  __syncthreads();
  if (tid < 32) {
    int b = tid;
    float fp = pre[0 * 33 + b] + A.bf[h];
    float ip = pre[1 * 33 + b] + A.bi[h];
    float gp = pre[2 * 33 + b] + A.bg[h];
    float op = pre[3 * 33 + b] + A.bo[h];
    float ft = 1.f / (1.f + expf(-fp));
    float it = 1.f / (1.f + expf(-ip));
    float gt = tanhf(gp);
    float ot = 1.f / (1.f + expf(-op));
    float cn = ft * A.cT[h * 32 + b] + it * gt;
    A.cT[h * 32 + b] = cn;
    float hn = ot * tanhf(cn);
    A.houtA[h * 32 + b] = hn;
    A.houtB[h * 32 + b] = hn;
  }
}

template <int IN>
__global__ __launch_bounds__(512) void k_lstm(LstmArgs a) {
  __shared__ __align__(16) float wl[4 * 1028];
  __shared__ __align__(16) float gsum[4 * 16 * 36];
  __shared__ float pre[4 * 33];
  lstm_body<IN>(blockIdx.x, threadIdx.x, a, wl, gsum, pre);
}

// pipeline pair: blocks 0..511 run layer0 @ step t+1, 512..1023 layer1 @ step t
// (independent by dataflow: l0(t+1) needs h0(t), l1(t) needs h0(t),h1(t-1) --
// all written by the previous dispatch). 32 launches -> 17.
__global__ __launch_bounds__(512) void k_lstm_pair(LstmArgs a0, LstmArgs a1) {
  __shared__ __align__(16) float wl[4 * 1028];
  __shared__ __align__(16) float gsum[4 * 16 * 36];
  __shared__ float pre[4 * 33];
  if (blockIdx.x < 512)
    lstm_body<256>(blockIdx.x, threadIdx.x, a0, wl, gsum, pre);
  else
    lstm_body<512>(blockIdx.x - 512, threadIdx.x, a1, wl, gsum, pre);
}

// ---------------------------------------------------------------------------
// classifier: input h1T layout [h][b] (a comb slice)
__global__ void k_cls(const float* __restrict__ h1T, const float* __restrict__ cw1,
                      const float* __restrict__ cb1, const float* __restrict__ cw2,
                      const float* __restrict__ cb2, const float* __restrict__ cw3,
                      const float* __restrict__ cb3, float* __restrict__ out) {
  __shared__ float hv[512];
  __shared__ float y1[128];
  __shared__ float y2[64];
  int b = blockIdx.x, tid = threadIdx.x;
  for (int i = tid; i < 512; i += 128) hv[i] = h1T[i * 32 + b];
  __syncthreads();
  float s = cb1[tid];
  for (int k = 0; k < 512; ++k) s += hv[k] * cw1[k * 128 + tid];
  y1[tid] = fmaxf(s, 0.f);
  __syncthreads();
  if (tid < 64) {
    float s2 = cb2[tid];
    for (int k = 0; k < 128; ++k) s2 += y1[k] * cw2[k * 64 + tid];
    y2[tid] = fmaxf(s2, 0.f);
  }
  __syncthreads();
  if (tid < 6) {
    float s3 = cb3[tid];
    for (int k = 0; k < 64; ++k) s3 += y2[k] * cw3[k * 6 + tid];
    out[b * 6 + tid] = s3;
  }
}

// ---------------------------------------------------------------------------
// Workspace (floats):
//  region0 [0..8,388,608) = a1 (conv1 out, dead after conv2); then reused:
//    wt    @ 0          [3,670,016]
//    comb0 @ 3,670,016  [17*768*32  = 417,792]   comb0[t] = [emb(t), h0(t-1)]
//    comb1 @ 4,087,808  [17*1024*32 = 557,056]   comb1[t] = [h0(t), h1(t-1)]
//    c0    @ 4,644,864  [16,384];  c1 @ 4,661,248 [16,384]
//  a2  @ 8,388,608  [4,194,304]   layout [n][px][oc]
//  w2t @ 12,582,912 [4,608];  w3t @ 12,587,520 [73,728]
extern "C" void kernel_launch(void* const* d_in, const int* in_sizes, int n_in,
                              void* d_out, int out_size, void* d_ws, size_t ws_size,
                              hipStream_t stream) {
  const float* x  = (const float*)d_in[0];
  const float* w1 = (const float*)d_in[1];
  const float* b1 = (const float*)d_in[2];
  const float* w2 = (const float*)d_in[3];
  const float* b2 = (const float*)d_in[4];
  const float* w3 = (const float*)d_in[5];
  const float* b3 = (const float*)d_in[6];
  const float* cw1 = (const float*)d_in[23];
  const float* cb1 = (const float*)d_in[24];
  const float* cw2 = (const float*)d_in[25];
  const float* cb2 = (const float*)d_in[26];
  const float* cw3 = (const float*)d_in[27];
  const float* cb3 = (const float*)d_in[28];

  float* ws = (float*)d_ws;
  float* a1    = ws;
  float* wt    = ws;
  float* comb0 = ws + 3670016;
  float* comb1 = ws + 4087808;
  float* c0    = ws + 4644864;
  float* c1    = ws + 4661248;
  float* a2    = ws + 8388608;
  float* w2t   = ws + 12582912;
  float* w3t   = ws + 12587520;
  const int C0 = 768 * 32, C1 = 1024 * 32;

  k_prep_w<<<288, 256, 0, stream>>>(w2, w2t, w3, w3t);
  k_conv1<<<32768, 256, 0, stream>>>(x, w1, b1, a1);
  k_conv2<<<dim3(512, 2), 256, 0, stream>>>(a1, w2t, b2, a2);
  // a1 now dead; everything below may write region0

  hipMemsetAsync(comb0 + 256 * 32, 0, (size_t)512 * 32 * 4, stream);
  hipMemsetAsync(comb1 + 512 * 32, 0, (size_t)512 * 32 * 4, stream);
  hipMemsetAsync(c0, 0, (size_t)2 * 512 * 32 * 4, stream);

  k_conv3<<<dim3(512, 2), 512, 0, stream>>>(a2, w3t, b3, comb0);

  TPtrs tp;
  for (int g = 0; g < 4; ++g) {
    tp.in[g]      = (const float*)d_in[7 + 2 * g];
    tp.out[g]     = wt + g * (512 * 768);
    tp.in[4 + g]  = (const float*)d_in[15 + 2 * g];
    tp.out[4 + g] = wt + 4 * (512 * 768) + g * (512 * 1024);
  }
  k_transpose<<<dim3(32, 16, 8), dim3(32, 8), 0, stream>>>(tp);

  const float* wl0[4] = {wt, wt + 393216, wt + 786432, wt + 1179648};
  float* l1base = wt + 1572864;
  const float* wl1[4] = {l1base, l1base + 524288, l1base + 1048576, l1base + 1572864};

  auto L0 = [&](int t) {
    LstmArgs a;
    a.comb = comb0 + (size_t)t * C0;
    a.houtA = comb0 + (size_t)(t + 1) * C0 + 256 * 32;
    a.houtB = comb1 + (size_t)t * C1;
    a.cT = c0;
    a.Wf = wl0[0]; a.Wi = wl0[1]; a.Wg = wl0[2]; a.Wo = wl0[3];
    a.bf = (const float*)d_in[8];  a.bi = (const float*)d_in[10];
    a.bg = (const float*)d_in[12]; a.bo = (const float*)d_in[14];
    return a;
  };
  auto L1 = [&](int t) {
    LstmArgs a;
    a.comb = comb1 + (size_t)t * C1;
    a.houtA = comb1 + (size_t)(t + 1) * C1 + 512 * 32;
    a.houtB = a.houtA;
    a.cT = c1;
    a.Wf = wl1[0]; a.Wi = wl1[1]; a.Wg = wl1[2]; a.Wo = wl1[3];
    a.bf = (const float*)d_in[16]; a.bi = (const float*)d_in[18];
    a.bg = (const float*)d_in[20]; a.bo = (const float*)d_in[22];
    return a;
  };

  k_lstm<256><<<512, 512, 0, stream>>>(L0(0));
  for (int p = 0; p < 15; ++p)
    k_lstm_pair<<<1024, 512, 0, stream>>>(L0(p + 1), L1(p));
  k_lstm<512><<<512, 512, 0, stream>>>(L1(15));

  k_cls<<<32, 128, 0, stream>>>(comb1 + (size_t)16 * C1 + 512 * 32,
                                cw1, cb1, cw2, cb2, cw3, cb3, (float*)d_out);
}